// Round 5
// baseline (468.783 us; speedup 1.0000x reference)
//
#include <hip/hip_runtime.h>

// Problem constants
constexpr int BB = 1024;   // batch
constexpr int GG = 2000;   // genes
constexpr int SS = 32;     // per-gene width
constexpr int K1 = 4096, K2 = 2048, K3 = 1024;
constexpr int XROW = GG * SS;             // 64000 floats per x row
constexpr int GPAD = 2048;                // padded gene width (zeros beyond 2000)

constexpr int BH = BB * 64;               // 65536 floats

// workspace layout (floats)
constexpr int Y1P_OFF = 0;                // 4 split-K slabs
constexpr int Y2P_OFF = 4 * BH;           // 2 slabs
constexpr int Y3P_OFF = 6 * BH;           // 1 slab
constexpr int HP_OFF  = 7 * BH;           // 4 fc0 split-K slabs
constexpr int GP_OFF  = 11 * BH;          // gene matrix [1024][2048], zero-padded

constexpr int NGEMM_BLK = 224;            // 128 (Y1) + 64 (Y2) + 32 (Y3)
constexpr int NGENE_BLK = 1024;           // 8 gene supergroups x 128 row-blocks(8 rows)
constexpr int KCH       = 1024;           // z-GEMM split-K chunk

// ---------------- k1: copy-shaped gene stream + z-GEMMs ----------------
__global__ __launch_bounds__(256, 4) void k1_gene_zgemm(
    const float* __restrict__ x,  const float* __restrict__ z1,
    const float* __restrict__ z2, const float* __restrict__ z3,
    const float* __restrict__ Wg, const float* __restrict__ bg,
    const float* __restrict__ W1, const float* __restrict__ W2,
    const float* __restrict__ W3, float* __restrict__ ws)
{
    __shared__ float lds[32 * 36 + 32 * 68];   // gemm-only: zt + wt, 13.3 KB
    const int bid = blockIdx.x;
    const int t   = threadIdx.x;

    if (bid >= NGEMM_BLK) {
        // ----- gene stream: lane owns one gene, loops 8 rows, no LDS/barriers -----
        const int gid = bid - NGEMM_BLK;       // 0..1023
        const int sg  = gid >> 7;              // 0..7  gene supergroup (256 genes)
        const int rb  = gid & 127;             // 0..127 row block (8 rows)
        const int g   = sg * 256 + t;          // 0..2047
        const bool gv = (g < GG);
        const int gcl = gv ? g : 0;

        float4 wg[8];
        #pragma unroll
        for (int c = 0; c < 8; ++c)
            wg[c] = *(const float4*)(Wg + (size_t)gcl * SS + c * 4);
        const float bias = bg[gcl];

        const float* xp = x + (size_t)(rb * 8) * XROW + (size_t)gcl * SS;
        float* gp = ws + GP_OFF + (size_t)(rb * 8) * GPAD + sg * 256 + t;

        #pragma unroll
        for (int it = 0; it < 4; ++it) {       // 2 rows per iteration
            const float* pa = xp + (size_t)(it * 2) * XROW;
            const float* pb = pa + XROW;
            float4 xa[8], xb[8];
            #pragma unroll
            for (int c = 0; c < 8; ++c) xa[c] = *(const float4*)(pa + c * 4);
            #pragma unroll
            for (int c = 0; c < 8; ++c) xb[c] = *(const float4*)(pb + c * 4);

            float ax = 0.f, ay = 0.f, az = 0.f, aw = 0.f;
            float bx = 0.f, by = 0.f, bz = 0.f, bw = 0.f;
            #pragma unroll
            for (int c = 0; c < 8; ++c) {
                ax = fmaf(xa[c].x, wg[c].x, ax); ay = fmaf(xa[c].y, wg[c].y, ay);
                az = fmaf(xa[c].z, wg[c].z, az); aw = fmaf(xa[c].w, wg[c].w, aw);
                bx = fmaf(xb[c].x, wg[c].x, bx); by = fmaf(xb[c].y, wg[c].y, by);
                bz = fmaf(xb[c].z, wg[c].z, bz); bw = fmaf(xb[c].w, wg[c].w, bw);
            }
            const float sa = (ax + ay) + (az + aw);
            const float sb = (bx + by) + (bz + bw);
            gp[(size_t)(it * 2) * GPAD]     = gv ? fmaxf(sa + bias, 0.f) : 0.f;
            gp[(size_t)(it * 2 + 1) * GPAD] = gv ? fmaxf(sb + bias, 0.f) : 0.f;
        }
    } else {
        // ----- z-GEMM block: 32m x 64n tile, K-chunk 32, padded LDS -----
        const int id = bid;                    // 0..223
        const float* z; const float* W; int K; int mt; int kslab; float* ys;
        if (id < 128)      { z = z1; W = W1; K = K1; mt = id >> 2; kslab = id & 3;
                             ys = ws + Y1P_OFF + (size_t)kslab * BH; }
        else if (id < 192) { int l = id - 128; z = z2; W = W2; K = K2; mt = l >> 1; kslab = l & 1;
                             ys = ws + Y2P_OFF + (size_t)kslab * BH; }
        else               { int l = id - 192; z = z3; W = W3; K = K3; mt = l; kslab = 0;
                             ys = ws + Y3P_OFF; }

        const int m0    = mt * 32;
        const int kbase = kslab * KCH;
        const int n2    = t & 31;
        const int mq    = t >> 5;
        float* zt = lds;                       // [32][36]
        float* wt = lds + 32 * 36;             // [32][68]

        float2 acc[4];
        #pragma unroll
        for (int j = 0; j < 4; ++j) acc[j] = make_float2(0.f, 0.f);

        const int zr = t >> 3, zc = (t & 7) * 4;
        for (int kc = 0; kc < KCH / 32; ++kc) {
            const int k0 = kbase + kc * 32;
            *(float4*)&zt[zr * 36 + zc] =
                *(const float4*)&z[(size_t)(m0 + zr) * K + k0 + zc];
            #pragma unroll
            for (int r = 0; r < 2; ++r) {
                const int idx = t + r * 256;
                const int row = idx >> 4;
                const int c4  = (idx & 15) * 4;
                *(float4*)&wt[row * 68 + c4] =
                    *(const float4*)&W[(size_t)(k0 + row) * 64 + c4];
            }
            __syncthreads();
            #pragma unroll
            for (int kk = 0; kk < 32; kk += 4) {
                const float2 wv0 = *(const float2*)&wt[(kk + 0) * 68 + n2 * 2];
                const float2 wv1 = *(const float2*)&wt[(kk + 1) * 68 + n2 * 2];
                const float2 wv2 = *(const float2*)&wt[(kk + 2) * 68 + n2 * 2];
                const float2 wv3 = *(const float2*)&wt[(kk + 3) * 68 + n2 * 2];
                #pragma unroll
                for (int j = 0; j < 4; ++j) {
                    const float4 zj = *(const float4*)&zt[(mq * 4 + j) * 36 + kk];
                    acc[j].x = fmaf(zj.x, wv0.x, acc[j].x); acc[j].y = fmaf(zj.x, wv0.y, acc[j].y);
                    acc[j].x = fmaf(zj.y, wv1.x, acc[j].x); acc[j].y = fmaf(zj.y, wv1.y, acc[j].y);
                    acc[j].x = fmaf(zj.z, wv2.x, acc[j].x); acc[j].y = fmaf(zj.z, wv2.y, acc[j].y);
                    acc[j].x = fmaf(zj.w, wv3.x, acc[j].x); acc[j].y = fmaf(zj.w, wv3.y, acc[j].y);
                }
            }
            __syncthreads();
        }
        #pragma unroll
        for (int j = 0; j < 4; ++j)
            *(float2*)&ys[(size_t)(m0 + mq * 4 + j) * 64 + n2 * 2] = acc[j];
    }
}

// ---------------- k2: fc0 GEMM over padded gene matrix (split-K 4x512) ----------------
__global__ __launch_bounds__(256, 4) void k2_fc0_gemm(
    const float* __restrict__ ws_c, const float* __restrict__ W0,
    float* __restrict__ ws)
{
    __shared__ float lds[32 * 36 + 32 * 68];
    const int t  = threadIdx.x;
    const int mt  = blockIdx.x >> 2;          // 0..31
    const int ksl = blockIdx.x & 3;           // 0..3
    const int m0    = mt * 32;
    const int kbase = ksl * 512;

    const float* gene = ws_c + GP_OFF;        // [1024][2048], zero-padded cols
    float* hp = ws + HP_OFF + (size_t)ksl * BH;

    const int n2 = t & 31;
    const int mq = t >> 5;
    float* zt = lds;
    float* wt = lds + 32 * 36;

    float2 acc[4];
    #pragma unroll
    for (int j = 0; j < 4; ++j) acc[j] = make_float2(0.f, 0.f);

    const int zr = t >> 3, zc = (t & 7) * 4;
    for (int kc = 0; kc < 16; ++kc) {
        const int k0 = kbase + kc * 32;
        *(float4*)&zt[zr * 36 + zc] =
            *(const float4*)&gene[(size_t)(m0 + zr) * GPAD + k0 + zc];
        #pragma unroll
        for (int r = 0; r < 2; ++r) {
            const int idx = t + r * 256;
            const int row = idx >> 4;
            const int c4  = (idx & 15) * 4;
            int krow = k0 + row; if (krow >= GG) krow = GG - 1;  // pad-safe (gene=0)
            *(float4*)&wt[row * 68 + c4] =
                *(const float4*)&W0[(size_t)krow * 64 + c4];
        }
        __syncthreads();
        #pragma unroll
        for (int kk = 0; kk < 32; kk += 4) {
            const float2 wv0 = *(const float2*)&wt[(kk + 0) * 68 + n2 * 2];
            const float2 wv1 = *(const float2*)&wt[(kk + 1) * 68 + n2 * 2];
            const float2 wv2 = *(const float2*)&wt[(kk + 2) * 68 + n2 * 2];
            const float2 wv3 = *(const float2*)&wt[(kk + 3) * 68 + n2 * 2];
            #pragma unroll
            for (int j = 0; j < 4; ++j) {
                const float4 zj = *(const float4*)&zt[(mq * 4 + j) * 36 + kk];
                acc[j].x = fmaf(zj.x, wv0.x, acc[j].x); acc[j].y = fmaf(zj.x, wv0.y, acc[j].y);
                acc[j].x = fmaf(zj.y, wv1.x, acc[j].x); acc[j].y = fmaf(zj.y, wv1.y, acc[j].y);
                acc[j].x = fmaf(zj.z, wv2.x, acc[j].x); acc[j].y = fmaf(zj.z, wv2.y, acc[j].y);
                acc[j].x = fmaf(zj.w, wv3.x, acc[j].x); acc[j].y = fmaf(zj.w, wv3.y, acc[j].y);
            }
        }
        __syncthreads();
    }
    #pragma unroll
    for (int j = 0; j < 4; ++j)
        *(float2*)&hp[(size_t)(m0 + mq * 4 + j) * 64 + n2 * 2] = acc[j];
}

// ---------------- k3: reduce partials + fusion + tiny MLP ----------------
__global__ __launch_bounds__(256, 4) void k3_combine_mlp(
    const float* __restrict__ ws,
    const float* __restrict__ b0v,
    const float* __restrict__ b1v, const float* __restrict__ b2v,
    const float* __restrict__ b3v,
    const float* __restrict__ w1v, const float* __restrict__ w2v,
    const float* __restrict__ w3v,
    const float* __restrict__ fW1, const float* __restrict__ fb1,
    const float* __restrict__ fW2, const float* __restrict__ fb2,
    const float* __restrict__ fW3, const float* __restrict__ fb3,
    float* __restrict__ out)
{
    const float* Y1p = ws + Y1P_OFF;
    const float* Y2p = ws + Y2P_OFF;
    const float* Y3p = ws + Y3P_OFF;
    const float* Hp  = ws + HP_OFF;

    const int t   = threadIdx.x;
    const int n   = t & 63;
    const int w   = t >> 6;
    const int row = blockIdx.x * 4 + w;
    const int rn  = row * 64 + n;

    const float h = Hp[rn] + Hp[BH + rn] + Hp[2 * BH + rn] + Hp[3 * BH + rn];
    const float h0 = fmaxf(h + b0v[n], 0.f);

    const float y1 = Y1p[rn] + Y1p[BH + rn] + Y1p[2 * BH + rn] + Y1p[3 * BH + rn];
    float d = fmaf(fmaxf(y1 + b1v[n], 0.f), w1v[n], h0);
    const float y2 = Y2p[rn] + Y2p[BH + rn];
    d = fmaf(fmaxf(y2 + b2v[n], 0.f), w2v[n], d);
    const float y3 = Y3p[rn];
    d = fmaf(fmaxf(y3 + b3v[n], 0.f), w3v[n], d);

    __shared__ float sd[4][64];
    __shared__ float sh[4][64];
    sd[w][n] = d;
    __syncthreads();
    float a1 = fb1[n];
    #pragma unroll 8
    for (int j = 0; j < 64; ++j) a1 = fmaf(sd[w][j], fW1[j * 64 + n], a1);
    a1 = fmaxf(a1, 0.f);
    sh[w][n] = a1;
    __syncthreads();
    float a2 = fb2[n];
    #pragma unroll 8
    for (int j = 0; j < 64; ++j) a2 = fmaf(sh[w][j], fW2[j * 64 + n], a2);
    a2 = fmaxf(a2, 0.f);

    float v = a2 * fW3[n];
    #pragma unroll
    for (int o = 32; o > 0; o >>= 1) v += __shfl_xor(v, o);
    if (n == 0) out[row] = v + fb3[0];
}

extern "C" void kernel_launch(void* const* d_in, const int* in_sizes, int n_in,
                              void* d_out, int out_size, void* d_ws, size_t ws_size,
                              hipStream_t stream)
{
    const float* x   = (const float*)d_in[0];
    const float* z1  = (const float*)d_in[1];
    const float* z2  = (const float*)d_in[2];
    const float* z3  = (const float*)d_in[3];
    const float* Wg  = (const float*)d_in[4];
    const float* bg  = (const float*)d_in[5];
    const float* W0  = (const float*)d_in[6];
    const float* b0v = (const float*)d_in[7];
    const float* W1  = (const float*)d_in[8];
    const float* b1v = (const float*)d_in[9];
    const float* W2  = (const float*)d_in[10];
    const float* b2v = (const float*)d_in[11];
    const float* W3  = (const float*)d_in[12];
    const float* b3v = (const float*)d_in[13];
    const float* w1v = (const float*)d_in[14];
    const float* w2v = (const float*)d_in[15];
    const float* w3v = (const float*)d_in[16];
    const float* fW1 = (const float*)d_in[17];
    const float* fb1 = (const float*)d_in[18];
    const float* fW2 = (const float*)d_in[19];
    const float* fb2 = (const float*)d_in[20];
    const float* fW3 = (const float*)d_in[21];
    const float* fb3 = (const float*)d_in[22];

    float* ws  = (float*)d_ws;
    float* out = (float*)d_out;

    k1_gene_zgemm<<<dim3(NGEMM_BLK + NGENE_BLK), dim3(256), 0, stream>>>(
        x, z1, z2, z3, Wg, bg, W1, W2, W3, ws);

    k2_fc0_gemm<<<dim3(128), dim3(256), 0, stream>>>(ws, W0, ws);

    k3_combine_mlp<<<dim3(BB / 4), dim3(256), 0, stream>>>(
        ws, b0v, b1v, b2v, b3v, w1v, w2v, w3v,
        fW1, fb1, fW2, fb2, fW3, fb3, out);
}